// Round 16
// baseline (415.641 us; speedup 1.0000x reference)
//
#include <hip/hip_runtime.h>
#include <hip/hip_bf16.h>
#include <math.h>

#define PHI_F     1.618033988749895f
#define LUT_N     4096
#define LUT_INV   651.8986469044033f      /* 4096/(2*pi) rounded to f32 */
#define LUT_STEP  0.0015339807878856412f  /* 2*pi/4096  rounded to f32 */

#define B_  8
#define S_  512
#define D_  64
#define H_  4
#define DH_ 16
#define N_  128
#define V_  32000
#define R_  (B_ * S_)   /* 4096 rows */

typedef __attribute__((ext_vector_type(8))) short short8_t;
typedef __attribute__((ext_vector_type(4))) float f32x4;

// ---------------------------------------------------------------- LUT interp (float2 {sin,cos})
__device__ __forceinline__ void lut2(const float2* __restrict__ sc,
                                     float th, float& s, float& c) {
    float pos = th * LUT_INV;
    float f0  = floorf(pos);
    float fr  = pos - f0;
    int   i0  = ((int)f0) & (LUT_N - 1);
    int   i1  = (i0 + 1) & (LUT_N - 1);
    float2 p0 = sc[i0];
    float2 p1 = sc[i1];
    float om  = 1.0f - fr;
    s = p0.x * om + p1.x * fr;
    c = p0.y * om + p1.y * fr;
}

// ---------------------------------------------------------------- table build
// scT2[i] = {s_i, c_i};  scT4[i] = {s_i, c_i, s_{i+1}, c_{i+1}} (duplicated
// neighbor -> scan needs only one ds_read_b128 per eval).
__global__ void k_tables(float2* __restrict__ scT2, float4* __restrict__ scT4) {
    int i = blockIdx.x * blockDim.x + threadIdx.x;
    if (i < LUT_N) {
        float g = (float)i * LUT_STEP;        // matches np.arange(f32) * (2pi/4096)
        float s = (float)sin((double)g);
        float c = (float)cos((double)g);
        scT2[i] = make_float2(s, c);
        *(float2*)&scT4[i] = make_float2(s, c);                       // .x .y
        *(((float2*)&scT4[(i - 1) & (LUT_N - 1)]) + 1) = make_float2(s, c); // .z .w
    }
}

// ---------------------------------------------------------------- fused stage 0
// blocks 0-7: scan (in-kernel gather; NOTHING extra on the 1-wave serial path)
// blocks 8-2007: wout->bf16; blocks 2008+: resid weight prep
__global__ __launch_bounds__(256) void k_fused0(
        const int* __restrict__ ids, const float* __restrict__ emb,
        const float* __restrict__ Wres, const float* __restrict__ Bres,
        const float* __restrict__ wpr, const float* __restrict__ wpi,
        const float* __restrict__ wout, const float4* __restrict__ scT4,
        float* __restrict__ states, __hip_bfloat16* __restrict__ wb,
        float2* __restrict__ ibres, float2* __restrict__ wpT) {
    int blk = blockIdx.x;
    int tid = threadIdx.x;
    if (blk >= 8) {
        if (blk < 2008) {                       // ---- wout -> bf16
            int i = (blk - 8) * 256 + tid;      // < 512000 float4s exactly
            float4 v = ((const float4*)wout)[i];
            union { __hip_bfloat16 h[4]; short4 s4; } u;
            u.h[0] = __float2bfloat16(v.x);
            u.h[1] = __float2bfloat16(v.y);
            u.h[2] = __float2bfloat16(v.z);
            u.h[3] = __float2bfloat16(v.w);
            *(short4*)(&wb[4 * (size_t)i]) = u.s4;
        } else {                                // ---- resid weight prep
            int idx = (blk - 2008) * 256 + tid; // < 8192 exactly
            ibres[idx] = make_float2(1.0f / (1.0f + fabsf(Wres[idx])), Bres[idx]);
            int nn = idx >> 6, d = idx & 63;
            wpT[idx] = make_float2(wpr[d * N_ + nn], wpi[d * N_ + nn]);
        }
        return;
    }
    // ---- scan. NUMERICS-CRITICAL: marginally-stable recurrence; carried
    // chain ops bit-identical to reference (exact div, same add/interp order;
    // float4 table holds the SAME values -> same bits).
    __shared__ float4 sc4[LUT_N];               // 64 KB exactly (static limit)
    for (int i = tid; i < LUT_N; i += 256) sc4[i] = scT4[i];
    __syncthreads();
    if (tid >= 64) return;
    int d = tid, b = blk;
    const int* idp = ids + b * S_;              // uniform scalar loads, off-chain
    float cw[8], cb[8];
#pragma unroll
    for (int j = 0; j < 8; ++j) {
        int id = idp[j];
        cw[j] = emb[(size_t)id * 128 + d];
        cb[j] = emb[(size_t)id * 128 + 64 + d];
    }
    float* outp = states + (size_t)b * S_ * D_ + d;
    float hr = 0.0f, hi = 0.0f;
    for (int tc = 0; tc < S_; tc += 8) {
        float nw[8], nb[8], res[8];
#pragma unroll
        for (int jj = 0; jj < 8; ++jj) {        // prefetch next 8 (wraps; unused)
            int id = idp[(tc + 8 + jj) & (S_ - 1)];
            nw[jj] = emb[(size_t)id * 128 + d];
            nb[jj] = emb[(size_t)id * 128 + 64 + d];
        }
#pragma unroll
        for (int jj = 0; jj < 8; ++jj) {
            int   t   = tc + jj;
            float wl  = 1.0f + fabsf(cw[jj]);
            float btv = cb[jj];
            float tp  = (float)t * PHI_F;
            float thr = hr / wl + btv + tp;     // order preserved: ((h/wl)+b)+tp
            float thi = hi / wl + btv + tp;
            float posr = thr * LUT_INV;
            float posi = thi * LUT_INV;
            float fr0 = floorf(posr), fi0 = floorf(posi);
            float frr = posr - fr0,   fri = posi - fi0;
            int   ir  = ((int)fr0) & (LUT_N - 1);
            int   ii  = ((int)fi0) & (LUT_N - 1);
            float4 pr = sc4[ir];                // one b128 per eval
            float4 pi = sc4[ii];
            float omr = 1.0f - frr, omi = 1.0f - fri;
            float sr = pr.x * omr + pr.z * frr;
            float cr = pr.y * omr + pr.w * frr;
            float si = pi.x * omi + pi.z * fri;
            float ci = pi.y * omi + pi.w * fri;
            float nr = cr * ci - sr * si;
            float ni = cr * si + sr * ci;
            hr = nr; hi = ni;
            res[jj] = nr + ni;
        }
#pragma unroll
        for (int jj = 0; jj < 8; ++jj) outp[(tc + jj) * D_] = res[jj];
#pragma unroll
        for (int jj = 0; jj < 8; ++jj) { cw[jj] = nw[jj]; cb[jj] = nb[jj]; }
    }
}

// ---------------------------------------------------------------- q/k build (k transposed)
// LUT read straight from global (L2-hot 32 KB): each thread does only 2
// evals, so a 32 KB per-block LDS staging would dominate the kernel.
__global__ __launch_bounds__(256) void k_qk(const float* __restrict__ states,
                                            const float* __restrict__ wq,
                                            const float* __restrict__ bq,
                                            const float* __restrict__ wk,
                                            const float* __restrict__ bk,
                                            const float2* __restrict__ scT,
                                            float* __restrict__ q,
                                            float* __restrict__ kT) {
    int idx = blockIdx.x * 256 + threadIdx.x;   // grid covers 262144 exactly
    int j  = idx & (DH_ - 1);
    int h  = (idx >> 4) & (H_ - 1);
    int bt = idx >> 6;
    int t  = bt & (S_ - 1);
    int b  = bt >> 9;
    float xp = states[idx];
    float tp = (float)t * PHI_F;
    int   hj = h * DH_ + j;
    float thq = xp / (1.0f + fabsf(wq[hj])) + bq[hj] + tp;
    float thk = xp / (1.0f + fabsf(wk[hj])) + bk[hj];
    float sq, cq, sk, ck;
    lut2(scT, thq, sq, cq);
    lut2(scT, thk, sk, ck);
    int base = bt * (H_ * 2 * DH_) + h * (2 * DH_) + j;
    q[base] = cq; q[base + DH_] = sq;
    size_t kb = ((size_t)(b * H_ + h) * 32 + j) * S_ + t;
    kT[kb] = ck; kT[kb + 16 * S_] = sk;
}

// ---------------------------------------------------------------- attention (t-tiled, TB=4)
#define TB_ 4
__global__ __launch_bounds__(256) void k_attn(const float* __restrict__ states,
                                              const float* __restrict__ q,
                                              const float* __restrict__ kT,
                                              const float* __restrict__ wctx,
                                              float* __restrict__ x) {
    __shared__ float ql[H_][TB_][2 * DH_];
    __shared__ float wlds[H_][TB_][S_];       // 32 KB
    __shared__ float cpart[4][TB_][D_];
    __shared__ float ctx[TB_][D_];
    int blk = blockIdx.x;                     // 8 * 128
    int b = blk >> 7, tile = blk & 127;
    int t0 = tile * TB_;
    int tid = threadIdx.x;
    int h = tid >> 6, l = tid & 63;
    if (l < 2 * DH_) {
#pragma unroll
        for (int tt = 0; tt < TB_; ++tt)
            ql[h][tt][l] = q[((b << 9) + t0 + tt) * 128 + h * 32 + l];
    }
    __syncthreads();

    const float* kTb = kT + (size_t)(b * H_ + h) * 32 * S_;
    float sc[8][TB_];
    float m[TB_];
#pragma unroll
    for (int tt = 0; tt < TB_; ++tt) m[tt] = -INFINITY;
#pragma unroll
    for (int jj = 0; jj < 8; ++jj) {
        int s = l + jj * 64;
        float a0 = 0.f, a1 = 0.f, a2 = 0.f, a3 = 0.f;
        if (s < t0 + TB_ - 1) {               // s < max t in tile
#pragma unroll
            for (int c = 0; c < 32; ++c) {
                float kv = kTb[c * S_ + s];
                a0 = fmaf(kv, ql[h][0][c], a0);
                a1 = fmaf(kv, ql[h][1][c], a1);
                a2 = fmaf(kv, ql[h][2][c], a2);
                a3 = fmaf(kv, ql[h][3][c], a3);
            }
        }
        const float scale = 0.1767766952966369f;   // 1/sqrt(2*dh)
        float v0 = (s < t0 + 0) ? a0 * scale : -INFINITY;
        float v1 = (s < t0 + 1) ? a1 * scale : -INFINITY;
        float v2 = (s < t0 + 2) ? a2 * scale : -INFINITY;
        float v3 = (s < t0 + 3) ? a3 * scale : -INFINITY;
        sc[jj][0] = v0; m[0] = fmaxf(m[0], v0);
        sc[jj][1] = v1; m[1] = fmaxf(m[1], v1);
        sc[jj][2] = v2; m[2] = fmaxf(m[2], v2);
        sc[jj][3] = v3; m[3] = fmaxf(m[3], v3);
    }
#pragma unroll
    for (int tt = 0; tt < TB_; ++tt)
        for (int o = 32; o; o >>= 1) m[tt] = fmaxf(m[tt], __shfl_xor(m[tt], o));
    float sum[TB_] = {0.f, 0.f, 0.f, 0.f};
#pragma unroll
    for (int jj = 0; jj < 8; ++jj)
#pragma unroll
        for (int tt = 0; tt < TB_; ++tt) {
            float e = __expf(sc[jj][tt] - m[tt]);   // exp(-inf)=0 handles mask
            sc[jj][tt] = e; sum[tt] += e;
        }
#pragma unroll
    for (int tt = 0; tt < TB_; ++tt)
        for (int o = 32; o; o >>= 1) sum[tt] += __shfl_xor(sum[tt], o);
#pragma unroll
    for (int tt = 0; tt < TB_; ++tt) {
        float inv = 1.0f / sum[tt];
#pragma unroll
        for (int jj = 0; jj < 8; ++jj)
            wlds[h][tt][l + jj * 64] = sc[jj][tt] * inv;
    }
    __syncthreads();
    {
        int p = tid >> 6, d = tid & 63;
        float ac[TB_] = {0.f, 0.f, 0.f, 0.f};
        for (int s = p; s < t0 + TB_ - 1; s += 4) {
            float sv = states[(((size_t)b << 9) + s) * D_ + d];
#pragma unroll
            for (int tt = 0; tt < TB_; ++tt) {
                float w4 = wlds[0][tt][s] + wlds[1][tt][s]
                         + wlds[2][tt][s] + wlds[3][tt][s];
                if (s < t0 + tt) ac[tt] += w4 * sv;
            }
        }
#pragma unroll
        for (int tt = 0; tt < TB_; ++tt) cpart[p][tt][d] = ac[tt];
    }
    __syncthreads();
    {
        int tt = tid >> 6, dd = tid & 63;
        ctx[tt][dd] = cpart[0][tt][dd] + cpart[1][tt][dd]
                    + cpart[2][tt][dd] + cpart[3][tt][dd];
    }
    __syncthreads();
    {
        int tt = tid >> 6, dd = tid & 63;
        int t  = t0 + tt;
        size_t row = ((size_t)b << 9) + t;
        float base = states[row * D_ + dd];
        float val  = base;
        if (t > 0) {
            float y = 0.0f;
            const float* wr = wctx + dd * D_;
            for (int k = 0; k < D_; ++k) y += ctx[tt][k] * wr[k];
            val = base + y;
        }
        x[row * D_ + dd] = val;
    }
}

// ---------------------------------------------------------------- residual phase block
// 512 blocks x 256 thr, 8 rows each; all 8 xv rows batch-loaded upfront,
// 2 syncs/row.
__global__ __launch_bounds__(256) void k_resid(const float* __restrict__ x,
                                               const float2* __restrict__ ibres,
                                               const float2* __restrict__ wpT,
                                               const float2* __restrict__ scT,
                                               __hip_bfloat16* __restrict__ xb) {
    __shared__ float2 sc[LUT_N];
    __shared__ float xv8[8][D_];
    __shared__ float csum[N_], ssum[N_];
    __shared__ float part[4][D_];
    int tid = threadIdx.x;
    for (int i = tid; i < LUT_N; i += 256) sc[i] = scT[i];
    {
        int r2 = tid >> 5, o = tid & 31;
        size_t base = (size_t)(blockIdx.x * 8 + r2) * D_;
        xv8[r2][o]      = x[base + o];
        xv8[r2][o + 32] = x[base + o + 32];
    }
    int n  = tid >> 1;
    int d0 = (tid & 1) * 32;
    float2 ib[32];
#pragma unroll
    for (int dd = 0; dd < 32; ++dd) ib[dd] = ibres[n * D_ + d0 + dd];
    int g = tid >> 6, dl = tid & 63;
    __syncthreads();
    for (int r = 0; r < 8; ++r) {
        int bt = blockIdx.x * 8 + r;
        int t  = bt & (S_ - 1);
        float tp = (float)t * PHI_F;
        float cs = 0.0f, ss = 0.0f;
#pragma unroll
        for (int dd = 0; dd < 32; ++dd) {
            float th = fmaf(xv8[r][d0 + dd], ib[dd].x, ib[dd].y) + tp;
            float s, c;
            lut2(sc, th, s, c);
            cs += c; ss += s;
        }
        cs += __shfl_xor(cs, 1);
        ss += __shfl_xor(ss, 1);
        if ((tid & 1) == 0) { csum[n] = cs; ssum[n] = ss; }
        __syncthreads();
        float acc = 0.0f;
#pragma unroll
        for (int nn = 0; nn < 32; ++nn) {
            float2 w = wpT[(g * 32 + nn) * D_ + dl];
            acc = fmaf(csum[g * 32 + nn], w.x, fmaf(ssum[g * 32 + nn], w.y, acc));
        }
        part[g][dl] = acc;
        __syncthreads();
        if (tid < D_) {
            float pre = part[0][tid] + part[1][tid] + part[2][tid] + part[3][tid];
            float sig = 1.0f / (1.0f + __expf(-pre));
            xb[bt * D_ + tid] = __float2bfloat16(xv8[r][tid] + pre * sig);
        }
    }
}

// ---------------------------------------------------------------- output GEMM (bf16 MFMA)
// R8 measured-best config: tile 64M x 256N, 4 waves, LDS epilogue,
// NONTEMPORAL full-line stores. ~108 us (R10 probe).
__global__ __launch_bounds__(256) void k_out(const __hip_bfloat16* __restrict__ xb,
                                             const __hip_bfloat16* __restrict__ wb,
                                             float* __restrict__ out) {
    __shared__ float ot[64][132];
    int tid  = threadIdx.x;
    int wave = tid >> 6, l = tid & 63;
    int wr = wave >> 1, wc = wave & 1;
    int m0 = blockIdx.y * 64 + wr * 32;
    int r  = l & 15;
    int ks = (l >> 4) * 8;
    int kh = l >> 4;

    short8_t a[2][2];
#pragma unroll
    for (int mi = 0; mi < 2; ++mi)
#pragma unroll
        for (int kk = 0; kk < 2; ++kk)
            a[mi][kk] = *reinterpret_cast<const short8_t*>(
                xb + (size_t)(m0 + mi * 16 + r) * 64 + kk * 32 + ks);

    for (int ch = 0; ch < 2; ++ch) {
        int c0 = blockIdx.x * 256 + ch * 128 + wc * 64;
        short8_t b[4][2];
#pragma unroll
        for (int ni = 0; ni < 4; ++ni)
#pragma unroll
            for (int kk = 0; kk < 2; ++kk)
                b[ni][kk] = *reinterpret_cast<const short8_t*>(
                    wb + (size_t)(c0 + ni * 16 + r) * 64 + kk * 32 + ks);

        f32x4 acc[2][4];
#pragma unroll
        for (int mi = 0; mi < 2; ++mi)
#pragma unroll
            for (int ni = 0; ni < 4; ++ni) {
                acc[mi][ni] = (f32x4){0.f, 0.f, 0.f, 0.f};
                acc[mi][ni] = __builtin_amdgcn_mfma_f32_16x16x32_bf16(
                    a[mi][0], b[ni][0], acc[mi][ni], 0, 0, 0);
                acc[mi][ni] = __builtin_amdgcn_mfma_f32_16x16x32_bf16(
                    a[mi][1], b[ni][1], acc[mi][ni], 0, 0, 0);
            }

        if (ch) __syncthreads();          // ot reuse hazard
#pragma unroll
        for (int mi = 0; mi < 2; ++mi)
#pragma unroll
            for (int ni = 0; ni < 4; ++ni)
#pragma unroll
                for (int i = 0; i < 4; ++i)
                    ot[wr * 32 + mi * 16 + kh * 4 + i][wc * 64 + ni * 16 + r] = acc[mi][ni][i];
        __syncthreads();

        size_t rbase = blockIdx.y * 64;
        size_t cb    = (size_t)blockIdx.x * 256 + ch * 128;
#pragma unroll
        for (int j = 0; j < 8; ++j) {
            int idx = j * 256 + tid;      // 2048 float4s
            int row = idx >> 5, c4 = idx & 31;
            f32x4 v = *(const f32x4*)&ot[row][c4 * 4];
            __builtin_nontemporal_store(v,
                (f32x4*)&out[(rbase + row) * V_ + cb + c4 * 4]);
        }
    }
}

// ---------------------------------------------------------------- launcher
extern "C" void kernel_launch(void* const* d_in, const int* in_sizes, int n_in,
                              void* d_out, int out_size, void* d_ws, size_t ws_size,
                              hipStream_t stream) {
    const int*   ids  = (const int*)  d_in[0];
    const float* emb  = (const float*)d_in[1];
    const float* wq   = (const float*)d_in[2];
    const float* bq   = (const float*)d_in[3];
    const float* wk   = (const float*)d_in[4];
    const float* bk   = (const float*)d_in[5];
    const float* wctx = (const float*)d_in[6];
    const float* Wres = (const float*)d_in[7];
    const float* Bres = (const float*)d_in[8];
    const float* wpr  = (const float*)d_in[9];
    const float* wpi  = (const float*)d_in[10];
    const float* wout = (const float*)d_in[11];
    float* out = (float*)d_out;

    float* states = (float*)d_ws;                 // 262144
    float* qbuf   = states + R_ * D_;             // 524288
    float* kTbuf  = qbuf + R_ * 128;              // 524288 (b,h,32,S)
    float* xbuf   = kTbuf + B_ * H_ * 32 * S_;    // 262144
    __hip_bfloat16* wb = (__hip_bfloat16*)(xbuf + R_ * D_);  // 2,048,000 bf16
    __hip_bfloat16* xb = wb + (size_t)V_ * D_;    // 262,144 bf16
    float2* scT   = (float2*)(xb + R_ * D_);      // 4096 float2
    float2* ibres = scT + LUT_N;                  // 8192 float2
    float2* wpT   = ibres + N_ * D_;              // 8192 float2
    float4* scT4  = (float4*)(wpT + N_ * D_);     // 4096 float4 (16B-aligned)

    k_tables<<<16, 256, 0, stream>>>(scT, scT4);
    k_fused0<<<2040, 256, 0, stream>>>(ids, emb, Wres, Bres, wpr, wpi, wout, scT4,
                                       states, wb, ibres, wpT);
    // PROBE: qk/attn/resid each launched twice (all idempotent) — total-dur
    // delta vs R13's 320.8 measures the middle block exactly (rocprof top-5
    // is fill-blinded). R13 best-known config otherwise unchanged.
    k_qk    <<<1024, 256, 0, stream>>>(states, wq, bq, wk, bk, scT, qbuf, kTbuf);
    k_qk    <<<1024, 256, 0, stream>>>(states, wq, bq, wk, bk, scT, qbuf, kTbuf);
    k_attn  <<<1024, 256, 0, stream>>>(states, qbuf, kTbuf, wctx, xbuf);
    k_attn  <<<1024, 256, 0, stream>>>(states, qbuf, kTbuf, wctx, xbuf);
    k_resid <<<R_ / 8, 256, 0, stream>>>(xbuf, ibres, wpT, scT, xb);
    k_resid <<<R_ / 8, 256, 0, stream>>>(xbuf, ibres, wpT, scT, xb);
    k_out   <<<dim3(V_ / 256, R_ / 64), 256, 0, stream>>>(xb, wb, out);
}

// Round 17
// 289.941 us; speedup vs baseline: 1.4335x; 1.4335x over previous
//
#include <hip/hip_runtime.h>
#include <hip/hip_bf16.h>
#include <math.h>

#define PHI_F     1.618033988749895f
#define LUT_N     4096
#define LUT_INV   651.8986469044033f      /* 4096/(2*pi) rounded to f32 */
#define LUT_STEP  0.0015339807878856412f  /* 2*pi/4096  rounded to f32 */

#define B_  8
#define S_  512
#define D_  64
#define H_  4
#define DH_ 16
#define N_  128
#define V_  32000
#define R_  (B_ * S_)   /* 4096 rows */

typedef __attribute__((ext_vector_type(8))) short short8_t;
typedef __attribute__((ext_vector_type(4))) float f32x4;

// ---------------------------------------------------------------- LUT interp (float2 {sin,cos})
__device__ __forceinline__ void lut2(const float2* __restrict__ sc,
                                     float th, float& s, float& c) {
    float pos = th * LUT_INV;
    float f0  = floorf(pos);
    float fr  = pos - f0;
    int   i0  = ((int)f0) & (LUT_N - 1);
    int   i1  = (i0 + 1) & (LUT_N - 1);
    float2 p0 = sc[i0];
    float2 p1 = sc[i1];
    float om  = 1.0f - fr;
    s = p0.x * om + p1.x * fr;
    c = p0.y * om + p1.y * fr;
}

// ---------------------------------------------------------------- table build
// scT2[i] = {s_i, c_i};  scT4[i] = {s_i, c_i, s_{i+1}, c_{i+1}} (duplicated
// neighbor -> scan needs only one ds_read_b128 per eval).
__global__ void k_tables(float2* __restrict__ scT2, float4* __restrict__ scT4) {
    int i = blockIdx.x * blockDim.x + threadIdx.x;
    if (i < LUT_N) {
        float g = (float)i * LUT_STEP;        // matches np.arange(f32) * (2pi/4096)
        float s = (float)sin((double)g);
        float c = (float)cos((double)g);
        scT2[i] = make_float2(s, c);
        *(float2*)&scT4[i] = make_float2(s, c);                       // .x .y
        *(((float2*)&scT4[(i - 1) & (LUT_N - 1)]) + 1) = make_float2(s, c); // .z .w
    }
}

// ---------------------------------------------------------------- fused stage 0
// blocks 0-7: scan (in-kernel gather; NOTHING extra on the 1-wave serial path)
// blocks 8-2007: wout->bf16; blocks 2008+: resid weight prep
__global__ __launch_bounds__(256) void k_fused0(
        const int* __restrict__ ids, const float* __restrict__ emb,
        const float* __restrict__ Wres, const float* __restrict__ Bres,
        const float* __restrict__ wpr, const float* __restrict__ wpi,
        const float* __restrict__ wout, const float4* __restrict__ scT4,
        float* __restrict__ states, __hip_bfloat16* __restrict__ wb,
        float2* __restrict__ ibres, float2* __restrict__ wpT) {
    int blk = blockIdx.x;
    int tid = threadIdx.x;
    if (blk >= 8) {
        if (blk < 2008) {                       // ---- wout -> bf16
            int i = (blk - 8) * 256 + tid;      // < 512000 float4s exactly
            float4 v = ((const float4*)wout)[i];
            union { __hip_bfloat16 h[4]; short4 s4; } u;
            u.h[0] = __float2bfloat16(v.x);
            u.h[1] = __float2bfloat16(v.y);
            u.h[2] = __float2bfloat16(v.z);
            u.h[3] = __float2bfloat16(v.w);
            *(short4*)(&wb[4 * (size_t)i]) = u.s4;
        } else {                                // ---- resid weight prep
            int idx = (blk - 2008) * 256 + tid; // < 8192 exactly
            ibres[idx] = make_float2(1.0f / (1.0f + fabsf(Wres[idx])), Bres[idx]);
            int nn = idx >> 6, d = idx & 63;
            wpT[idx] = make_float2(wpr[d * N_ + nn], wpi[d * N_ + nn]);
        }
        return;
    }
    // ---- scan. NUMERICS-CRITICAL: marginally-stable recurrence; carried
    // chain ops bit-identical to reference (exact div, same add/interp order;
    // float4 table holds the SAME values -> same bits).
    __shared__ float4 sc4[LUT_N];               // 64 KB exactly (static limit)
    for (int i = tid; i < LUT_N; i += 256) sc4[i] = scT4[i];
    __syncthreads();
    if (tid >= 64) return;
    int d = tid, b = blk;
    const int* idp = ids + b * S_;              // uniform scalar loads, off-chain
    float cw[8], cb[8];
#pragma unroll
    for (int j = 0; j < 8; ++j) {
        int id = idp[j];
        cw[j] = emb[(size_t)id * 128 + d];
        cb[j] = emb[(size_t)id * 128 + 64 + d];
    }
    float* outp = states + (size_t)b * S_ * D_ + d;
    float hr = 0.0f, hi = 0.0f;
    for (int tc = 0; tc < S_; tc += 8) {
        float nw[8], nb[8], res[8];
#pragma unroll
        for (int jj = 0; jj < 8; ++jj) {        // prefetch next 8 (wraps; unused)
            int id = idp[(tc + 8 + jj) & (S_ - 1)];
            nw[jj] = emb[(size_t)id * 128 + d];
            nb[jj] = emb[(size_t)id * 128 + 64 + d];
        }
#pragma unroll
        for (int jj = 0; jj < 8; ++jj) {
            int   t   = tc + jj;
            float wl  = 1.0f + fabsf(cw[jj]);
            float btv = cb[jj];
            float tp  = (float)t * PHI_F;
            float thr = hr / wl + btv + tp;     // order preserved: ((h/wl)+b)+tp
            float thi = hi / wl + btv + tp;
            float posr = thr * LUT_INV;
            float posi = thi * LUT_INV;
            float fr0 = floorf(posr), fi0 = floorf(posi);
            float frr = posr - fr0,   fri = posi - fi0;
            int   ir  = ((int)fr0) & (LUT_N - 1);
            int   ii  = ((int)fi0) & (LUT_N - 1);
            float4 pr = sc4[ir];                // one b128 per eval
            float4 pi = sc4[ii];
            float omr = 1.0f - frr, omi = 1.0f - fri;
            float sr = pr.x * omr + pr.z * frr;
            float cr = pr.y * omr + pr.w * frr;
            float si = pi.x * omi + pi.z * fri;
            float ci = pi.y * omi + pi.w * fri;
            float nr = cr * ci - sr * si;
            float ni = cr * si + sr * ci;
            hr = nr; hi = ni;
            res[jj] = nr + ni;
        }
#pragma unroll
        for (int jj = 0; jj < 8; ++jj) outp[(tc + jj) * D_] = res[jj];
#pragma unroll
        for (int jj = 0; jj < 8; ++jj) { cw[jj] = nw[jj]; cb[jj] = nb[jj]; }
    }
}

// ---------------------------------------------------------------- q/k build (k transposed)
__global__ __launch_bounds__(256) void k_qk(const float* __restrict__ states,
                                            const float* __restrict__ wq,
                                            const float* __restrict__ bq,
                                            const float* __restrict__ wk,
                                            const float* __restrict__ bk,
                                            const float2* __restrict__ scT,
                                            float* __restrict__ q,
                                            float* __restrict__ kT) {
    int idx = blockIdx.x * 256 + threadIdx.x;   // grid covers 262144 exactly
    int j  = idx & (DH_ - 1);
    int h  = (idx >> 4) & (H_ - 1);
    int bt = idx >> 6;
    int t  = bt & (S_ - 1);
    int b  = bt >> 9;
    float xp = states[idx];
    float tp = (float)t * PHI_F;
    int   hj = h * DH_ + j;
    float thq = xp / (1.0f + fabsf(wq[hj])) + bq[hj] + tp;
    float thk = xp / (1.0f + fabsf(wk[hj])) + bk[hj];
    float sq, cq, sk, ck;
    lut2(scT, thq, sq, cq);
    lut2(scT, thk, sk, ck);
    int base = bt * (H_ * 2 * DH_) + h * (2 * DH_) + j;
    q[base] = cq; q[base + DH_] = sq;
    size_t kb = ((size_t)(b * H_ + h) * 32 + j) * S_ + t;
    kT[kb] = ck; kT[kb + 16 * S_] = sk;
}

// ---------------------------------------------------------------- attention (t-tiled, TB=4)
// Context phase restructured (R17): head-sum computed ONCE into wlds[0]
// (same add order -> bit-identical), then unroll-by-4 batched loads break
// the load->use serial chain; remainder keeps exact original predicate form.
#define TB_ 4
__global__ __launch_bounds__(256) void k_attn(const float* __restrict__ states,
                                              const float* __restrict__ q,
                                              const float* __restrict__ kT,
                                              const float* __restrict__ wctx,
                                              float* __restrict__ x) {
    __shared__ float ql[H_][TB_][2 * DH_];
    __shared__ float wlds[H_][TB_][S_];       // 32 KB
    __shared__ float cpart[4][TB_][D_];
    __shared__ float ctx[TB_][D_];
    int blk = blockIdx.x;                     // 8 * 128
    int b = blk >> 7, tile = blk & 127;
    int t0 = tile * TB_;
    int tid = threadIdx.x;
    int h = tid >> 6, l = tid & 63;
    if (l < 2 * DH_) {
#pragma unroll
        for (int tt = 0; tt < TB_; ++tt)
            ql[h][tt][l] = q[((b << 9) + t0 + tt) * 128 + h * 32 + l];
    }
    __syncthreads();

    const float* kTb = kT + (size_t)(b * H_ + h) * 32 * S_;
    float sc[8][TB_];
    float m[TB_];
#pragma unroll
    for (int tt = 0; tt < TB_; ++tt) m[tt] = -INFINITY;
#pragma unroll
    for (int jj = 0; jj < 8; ++jj) {
        int s = l + jj * 64;
        float a0 = 0.f, a1 = 0.f, a2 = 0.f, a3 = 0.f;
        if (s < t0 + TB_ - 1) {               // s < max t in tile
#pragma unroll
            for (int c = 0; c < 32; ++c) {
                float kv = kTb[c * S_ + s];
                a0 = fmaf(kv, ql[h][0][c], a0);
                a1 = fmaf(kv, ql[h][1][c], a1);
                a2 = fmaf(kv, ql[h][2][c], a2);
                a3 = fmaf(kv, ql[h][3][c], a3);
            }
        }
        const float scale = 0.1767766952966369f;   // 1/sqrt(2*dh)
        float v0 = (s < t0 + 0) ? a0 * scale : -INFINITY;
        float v1 = (s < t0 + 1) ? a1 * scale : -INFINITY;
        float v2 = (s < t0 + 2) ? a2 * scale : -INFINITY;
        float v3 = (s < t0 + 3) ? a3 * scale : -INFINITY;
        sc[jj][0] = v0; m[0] = fmaxf(m[0], v0);
        sc[jj][1] = v1; m[1] = fmaxf(m[1], v1);
        sc[jj][2] = v2; m[2] = fmaxf(m[2], v2);
        sc[jj][3] = v3; m[3] = fmaxf(m[3], v3);
    }
#pragma unroll
    for (int tt = 0; tt < TB_; ++tt)
        for (int o = 32; o; o >>= 1) m[tt] = fmaxf(m[tt], __shfl_xor(m[tt], o));
    float sum[TB_] = {0.f, 0.f, 0.f, 0.f};
#pragma unroll
    for (int jj = 0; jj < 8; ++jj)
#pragma unroll
        for (int tt = 0; tt < TB_; ++tt) {
            float e = __expf(sc[jj][tt] - m[tt]);   // exp(-inf)=0 handles mask
            sc[jj][tt] = e; sum[tt] += e;
        }
#pragma unroll
    for (int tt = 0; tt < TB_; ++tt)
        for (int o = 32; o; o >>= 1) sum[tt] += __shfl_xor(sum[tt], o);
#pragma unroll
    for (int tt = 0; tt < TB_; ++tt) {
        float inv = 1.0f / sum[tt];
#pragma unroll
        for (int jj = 0; jj < 8; ++jj)
            wlds[h][tt][l + jj * 64] = sc[jj][tt] * inv;
    }
    __syncthreads();
    // head-sum once, in place, same order ((w0+w1)+w2)+w3 -> bit-identical
    for (int i = tid; i < TB_ * S_; i += 256) {
        int tt = i >> 9, s = i & (S_ - 1);
        wlds[0][tt][s] = wlds[0][tt][s] + wlds[1][tt][s]
                       + wlds[2][tt][s] + wlds[3][tt][s];
    }
    __syncthreads();
    {
        int p = tid >> 6, d = tid & 63;
        float ac[TB_] = {0.f, 0.f, 0.f, 0.f};
        const float* sb = states + ((((size_t)b) << 9)) * D_ + d;
        int s = p;
        // main loop: all four s-values < t0 (s+12 < t0) -> predicates provably
        // true for every tt; per-tt accumulation order (s ascending) unchanged.
        for (; s + 12 < t0; s += 16) {
            float sv0 = sb[(s     ) * D_];
            float sv1 = sb[(s +  4) * D_];
            float sv2 = sb[(s +  8) * D_];
            float sv3 = sb[(s + 12) * D_];
#pragma unroll
            for (int tt = 0; tt < TB_; ++tt) {
                ac[tt] += wlds[0][tt][s     ] * sv0;
                ac[tt] += wlds[0][tt][s +  4] * sv1;
                ac[tt] += wlds[0][tt][s +  8] * sv2;
                ac[tt] += wlds[0][tt][s + 12] * sv3;
            }
        }
        // remainder: exact original predicated form
        for (; s < t0 + TB_ - 1; s += 4) {
            float sv = sb[s * D_];
#pragma unroll
            for (int tt = 0; tt < TB_; ++tt)
                if (s < t0 + tt) ac[tt] += wlds[0][tt][s] * sv;
        }
#pragma unroll
        for (int tt = 0; tt < TB_; ++tt) cpart[p][tt][d] = ac[tt];
    }
    __syncthreads();
    {
        int tt = tid >> 6, dd = tid & 63;
        ctx[tt][dd] = cpart[0][tt][dd] + cpart[1][tt][dd]
                    + cpart[2][tt][dd] + cpart[3][tt][dd];
    }
    __syncthreads();
    {
        int tt = tid >> 6, dd = tid & 63;
        int t  = t0 + tt;
        size_t row = ((size_t)b << 9) + t;
        float base = states[row * D_ + dd];
        float val  = base;
        if (t > 0) {
            float y = 0.0f;
            const float* wr = wctx + dd * D_;
            for (int k = 0; k < D_; ++k) y += ctx[tt][k] * wr[k];
            val = base + y;
        }
        x[row * D_ + dd] = val;
    }
}

// ---------------------------------------------------------------- residual phase block
// 512 blocks x 256 thr, 8 rows each; all 8 xv rows batch-loaded upfront,
// 2 syncs/row.
__global__ __launch_bounds__(256) void k_resid(const float* __restrict__ x,
                                               const float2* __restrict__ ibres,
                                               const float2* __restrict__ wpT,
                                               const float2* __restrict__ scT,
                                               __hip_bfloat16* __restrict__ xb) {
    __shared__ float2 sc[LUT_N];
    __shared__ float xv8[8][D_];
    __shared__ float csum[N_], ssum[N_];
    __shared__ float part[4][D_];
    int tid = threadIdx.x;
    for (int i = tid; i < LUT_N; i += 256) sc[i] = scT[i];
    {
        int r2 = tid >> 5, o = tid & 31;
        size_t base = (size_t)(blockIdx.x * 8 + r2) * D_;
        xv8[r2][o]      = x[base + o];
        xv8[r2][o + 32] = x[base + o + 32];
    }
    int n  = tid >> 1;
    int d0 = (tid & 1) * 32;
    float2 ib[32];
#pragma unroll
    for (int dd = 0; dd < 32; ++dd) ib[dd] = ibres[n * D_ + d0 + dd];
    int g = tid >> 6, dl = tid & 63;
    __syncthreads();
    for (int r = 0; r < 8; ++r) {
        int bt = blockIdx.x * 8 + r;
        int t  = bt & (S_ - 1);
        float tp = (float)t * PHI_F;
        float cs = 0.0f, ss = 0.0f;
#pragma unroll
        for (int dd = 0; dd < 32; ++dd) {
            float th = fmaf(xv8[r][d0 + dd], ib[dd].x, ib[dd].y) + tp;
            float s, c;
            lut2(sc, th, s, c);
            cs += c; ss += s;
        }
        cs += __shfl_xor(cs, 1);
        ss += __shfl_xor(ss, 1);
        if ((tid & 1) == 0) { csum[n] = cs; ssum[n] = ss; }
        __syncthreads();
        float acc = 0.0f;
#pragma unroll
        for (int nn = 0; nn < 32; ++nn) {
            float2 w = wpT[(g * 32 + nn) * D_ + dl];
            acc = fmaf(csum[g * 32 + nn], w.x, fmaf(ssum[g * 32 + nn], w.y, acc));
        }
        part[g][dl] = acc;
        __syncthreads();
        if (tid < D_) {
            float pre = part[0][tid] + part[1][tid] + part[2][tid] + part[3][tid];
            float sig = 1.0f / (1.0f + __expf(-pre));
            xb[bt * D_ + tid] = __float2bfloat16(xv8[r][tid] + pre * sig);
        }
    }
}

// ---------------------------------------------------------------- output GEMM (bf16 MFMA)
// R8 measured-best config: tile 64M x 256N, 4 waves, LDS epilogue,
// NONTEMPORAL full-line stores. ~108 us (R10 probe).
__global__ __launch_bounds__(256) void k_out(const __hip_bfloat16* __restrict__ xb,
                                             const __hip_bfloat16* __restrict__ wb,
                                             float* __restrict__ out) {
    __shared__ float ot[64][132];
    int tid  = threadIdx.x;
    int wave = tid >> 6, l = tid & 63;
    int wr = wave >> 1, wc = wave & 1;
    int m0 = blockIdx.y * 64 + wr * 32;
    int r  = l & 15;
    int ks = (l >> 4) * 8;
    int kh = l >> 4;

    short8_t a[2][2];
#pragma unroll
    for (int mi = 0; mi < 2; ++mi)
#pragma unroll
        for (int kk = 0; kk < 2; ++kk)
            a[mi][kk] = *reinterpret_cast<const short8_t*>(
                xb + (size_t)(m0 + mi * 16 + r) * 64 + kk * 32 + ks);

    for (int ch = 0; ch < 2; ++ch) {
        int c0 = blockIdx.x * 256 + ch * 128 + wc * 64;
        short8_t b[4][2];
#pragma unroll
        for (int ni = 0; ni < 4; ++ni)
#pragma unroll
            for (int kk = 0; kk < 2; ++kk)
                b[ni][kk] = *reinterpret_cast<const short8_t*>(
                    wb + (size_t)(c0 + ni * 16 + r) * 64 + kk * 32 + ks);

        f32x4 acc[2][4];
#pragma unroll
        for (int mi = 0; mi < 2; ++mi)
#pragma unroll
            for (int ni = 0; ni < 4; ++ni) {
                acc[mi][ni] = (f32x4){0.f, 0.f, 0.f, 0.f};
                acc[mi][ni] = __builtin_amdgcn_mfma_f32_16x16x32_bf16(
                    a[mi][0], b[ni][0], acc[mi][ni], 0, 0, 0);
                acc[mi][ni] = __builtin_amdgcn_mfma_f32_16x16x32_bf16(
                    a[mi][1], b[ni][1], acc[mi][ni], 0, 0, 0);
            }

        if (ch) __syncthreads();          // ot reuse hazard
#pragma unroll
        for (int mi = 0; mi < 2; ++mi)
#pragma unroll
            for (int ni = 0; ni < 4; ++ni)
#pragma unroll
                for (int i = 0; i < 4; ++i)
                    ot[wr * 32 + mi * 16 + kh * 4 + i][wc * 64 + ni * 16 + r] = acc[mi][ni][i];
        __syncthreads();

        size_t rbase = blockIdx.y * 64;
        size_t cb    = (size_t)blockIdx.x * 256 + ch * 128;
#pragma unroll
        for (int j = 0; j < 8; ++j) {
            int idx = j * 256 + tid;      // 2048 float4s
            int row = idx >> 5, c4 = idx & 31;
            f32x4 v = *(const f32x4*)&ot[row][c4 * 4];
            __builtin_nontemporal_store(v,
                (f32x4*)&out[(rbase + row) * V_ + cb + c4 * 4]);
        }
    }
}

// ---------------------------------------------------------------- launcher
extern "C" void kernel_launch(void* const* d_in, const int* in_sizes, int n_in,
                              void* d_out, int out_size, void* d_ws, size_t ws_size,
                              hipStream_t stream) {
    const int*   ids  = (const int*)  d_in[0];
    const float* emb  = (const float*)d_in[1];
    const float* wq   = (const float*)d_in[2];
    const float* bq   = (const float*)d_in[3];
    const float* wk   = (const float*)d_in[4];
    const float* bk   = (const float*)d_in[5];
    const float* wctx = (const float*)d_in[6];
    const float* Wres = (const float*)d_in[7];
    const float* Bres = (const float*)d_in[8];
    const float* wpr  = (const float*)d_in[9];
    const float* wpi  = (const float*)d_in[10];
    const float* wout = (const float*)d_in[11];
    float* out = (float*)d_out;

    float* states = (float*)d_ws;                 // 262144
    float* qbuf   = states + R_ * D_;             // 524288
    float* kTbuf  = qbuf + R_ * 128;              // 524288 (b,h,32,S)
    float* xbuf   = kTbuf + B_ * H_ * 32 * S_;    // 262144
    __hip_bfloat16* wb = (__hip_bfloat16*)(xbuf + R_ * D_);  // 2,048,000 bf16
    __hip_bfloat16* xb = wb + (size_t)V_ * D_;    // 262,144 bf16
    float2* scT   = (float2*)(xb + R_ * D_);      // 4096 float2
    float2* ibres = scT + LUT_N;                  // 8192 float2
    float2* wpT   = ibres + N_ * D_;              // 8192 float2
    float4* scT4  = (float4*)(wpT + N_ * D_);     // 4096 float4 (16B-aligned)

    k_tables<<<16, 256, 0, stream>>>(scT, scT4);
    k_fused0<<<2040, 256, 0, stream>>>(ids, emb, Wres, Bres, wpr, wpi, wout, scT4,
                                       states, wb, ibres, wpT);
    k_qk    <<<1024, 256, 0, stream>>>(states, wq, bq, wk, bk, scT, qbuf, kTbuf);
    k_attn  <<<1024, 256, 0, stream>>>(states, qbuf, kTbuf, wctx, xbuf);
    k_resid <<<R_ / 8, 256, 0, stream>>>(xbuf, ibres, wpT, scT, xb);
    k_out   <<<dim3(V_ / 256, R_ / 64), 256, 0, stream>>>(xb, wb, out);
}